// Round 3
// baseline (559.659 us; speedup 1.0000x reference)
//
#include <hip/hip_runtime.h>
#include <hip/hip_bf16.h>

// out[B,S,O] = A[B,S,I] @ W[O,I]^T * scales[O] + bias[O]
// M = 16384, N = 4096, K = 4096. Output fp32.
#define M_TOTAL 16384
#define N_TOTAL 4096
#define K_TOTAL 4096
#define NT (K_TOTAL / 64)  // 64 K-tiles of BK=64

typedef __attribute__((ext_vector_type(8))) short bf16x8;
typedef __attribute__((ext_vector_type(4))) float f32x4;
typedef __attribute__((ext_vector_type(8))) unsigned short u16x8;

__device__ __forceinline__ unsigned short f32_to_bf16_rne(float f) {
  union { float f; unsigned u; } c; c.f = f;
  unsigned u = c.u;
  u += 0x7FFFu + ((u >> 16) & 1u);
  return (unsigned short)(u >> 16);
}

__global__ void cvt_f32_bf16(const float* __restrict__ in, u16x8* __restrict__ out, int n8) {
  const int stride = gridDim.x * blockDim.x;
  for (int i = blockIdx.x * blockDim.x + threadIdx.x; i < n8; i += stride) {
    const float4* p = reinterpret_cast<const float4*>(in) + (size_t)2 * i;
    float4 v0 = p[0], v1 = p[1];
    u16x8 o;
    o[0] = f32_to_bf16_rne(v0.x); o[1] = f32_to_bf16_rne(v0.y);
    o[2] = f32_to_bf16_rne(v0.z); o[3] = f32_to_bf16_rne(v0.w);
    o[4] = f32_to_bf16_rne(v1.x); o[5] = f32_to_bf16_rne(v1.y);
    o[6] = f32_to_bf16_rne(v1.z); o[7] = f32_to_bf16_rne(v1.w);
    out[i] = o;
  }
}

__global__ void cvt_i32_bf16(const int* __restrict__ in, u16x8* __restrict__ out, int n8) {
  const int stride = gridDim.x * blockDim.x;
  for (int i = blockIdx.x * blockDim.x + threadIdx.x; i < n8; i += stride) {
    const int4* p = reinterpret_cast<const int4*>(in) + (size_t)2 * i;
    int4 v0 = p[0], v1 = p[1];
    u16x8 o;  // |w| <= 127: exact in bf16
    o[0] = f32_to_bf16_rne((float)v0.x); o[1] = f32_to_bf16_rne((float)v0.y);
    o[2] = f32_to_bf16_rne((float)v0.z); o[3] = f32_to_bf16_rne((float)v0.w);
    o[4] = f32_to_bf16_rne((float)v1.x); o[5] = f32_to_bf16_rne((float)v1.y);
    o[6] = f32_to_bf16_rne((float)v1.z); o[7] = f32_to_bf16_rne((float)v1.w);
    out[i] = o;
  }
}

// ======== 256x256 8-phase bf16 GEMM (T2+T3+T4+T5), B^T input ========
// R3 change vs R2: deepened pipeline to m201 steady state — 1 stage/phase at
// earliest-legal WAR slot, fence VM(6) (3 half-tiles in flight, was VM(4)/2).
#define GLOAD_LDS16(gp, lp)                                                \
  __builtin_amdgcn_global_load_lds(                                        \
      (const __attribute__((address_space(1))) void*)(gp),                 \
      (__attribute__((address_space(3))) void*)(lp), 16, 0, 0)

#define BAR() asm volatile("s_barrier" ::: "memory")
#define LGKM0() asm volatile("s_waitcnt lgkmcnt(0)" ::: "memory")
#define VM(n) asm volatile("s_waitcnt vmcnt(" #n ")" ::: "memory")

// LDS map (131072 B): buf b: A_h0 [0,16K) A_h1 [16K,32K) B_h0 [32K,48K) B_h1 [48K,64K); buf1 at +64K.
// Half-tile = 128 rows x 64 bf16 cols, row stride 128 B.
// Swizzle: element (r,c) at byte r*128 + ((c*2) ^ ((r&7)<<4))  (involution, 16B-block permute).
// gload_lds writes linearly; GLOBAL source is inverse-swizzled (rule #21):
// row = q*64 + w*8 + (l>>3), colblk = ((l&7) ^ (l>>3))*8.

__global__ __launch_bounds__(512, 2) void w8a16_gemm256(
    const unsigned short* __restrict__ A,   // [M][K] bf16
    const unsigned short* __restrict__ Bt,  // [N][K] bf16
    const float* __restrict__ scales, const float* __restrict__ bias,
    float* __restrict__ C) {
  __shared__ alignas(16) unsigned char lds[131072];

  const int tid = threadIdx.x;
  const int w = tid >> 6, l = tid & 63;
  const int wr = w >> 2, wc = w & 3;  // 2x4 wave grid; per-wave 128x64 output
  const int bn = blockIdx.x, bm = blockIdx.y;

  // --- staging (pre-inverse-swizzled global source) ---
  const int rowq = tid >> 3;                     // = w*8 + (l>>3), 0..63
  const int colb = ((l & 7) ^ (l >> 3)) << 3;    // col block in elems
  const unsigned short* pA = A + (size_t)(bm * 256 + rowq) * K_TOTAL + colb;
  const unsigned short* pB = Bt + (size_t)(bn * 256 + rowq) * K_TOTAL + colb;
  unsigned char* const ldsp = lds;
  const int woff = w << 10;  // per-wave stage dest offset

#define SDA(b_, h_) (ldsp + (b_) * 65536 + (h_) * 16384 + woff)
#define SDB(b_, h_) (ldsp + (b_) * 65536 + 32768 + (h_) * 16384 + woff)
#define STAGE_A(b_, h_, t_)                                                   \
  do {                                                                        \
    GLOAD_LDS16(pA + (size_t)((h_) * 128) * K_TOTAL + (t_) * 64, SDA(b_, h_));\
    GLOAD_LDS16(pA + (size_t)((h_) * 128 + 64) * K_TOTAL + (t_) * 64,         \
                SDA(b_, h_) + 8192);                                          \
  } while (0)
#define STAGE_B(b_, h_, t_)                                                   \
  do {                                                                        \
    GLOAD_LDS16(pB + (size_t)((h_) * 128) * K_TOTAL + (t_) * 64, SDB(b_, h_));\
    GLOAD_LDS16(pB + (size_t)((h_) * 128 + 64) * K_TOTAL + (t_) * 64,         \
                SDB(b_, h_) + 8192);                                          \
  } while (0)

  // --- fragment read addressing (swizzled) ---
  const int arow = ((l & 15) << 7) + ((((l >> 4) ^ (l & 7)) & 7) << 4);

  bf16x8 af[8];   // 4 m-frags x 2 k (current m-half)
  bf16x8 bfr[8];  // 4 n-frags x 2 k (whole tile, held across phases)
  f32x4 acc[8][4] = {{}};

#define RD_A(mh_)                                                             \
  do {                                                                        \
    const unsigned char* Ab_ = ldsp + bsel * 65536 + wr * 16384;              \
    _Pragma("unroll") for (int fm = 0; fm < 4; ++fm)                          \
        _Pragma("unroll") for (int kk = 0; kk < 2; ++kk)                      \
            af[fm * 2 + kk] = *(const bf16x8*)(Ab_ + ((mh_) * 4 + fm) * 2048 +\
                                               (arow ^ (kk << 6)));           \
  } while (0)
#define RD_B(nh_)                                                             \
  do {                                                                        \
    const unsigned char* Bb_ = ldsp + bsel * 65536 + 32768 +                  \
                               (wc >> 1) * 16384 + (wc & 1) * 8192;           \
    _Pragma("unroll") for (int fn = 0; fn < 2; ++fn)                          \
        _Pragma("unroll") for (int kk = 0; kk < 2; ++kk)                      \
            bfr[((nh_) * 2 + fn) * 2 + kk] =                                  \
                *(const bf16x8*)(Bb_ + ((nh_) * 2 + fn) * 2048 +              \
                                 (arow ^ (kk << 6)));                         \
  } while (0)
#define QUAD(mh_, nh_)                                                        \
  do {                                                                        \
    _Pragma("unroll") for (int m = 0; m < 4; ++m)                             \
        _Pragma("unroll") for (int n = 0; n < 2; ++n)                         \
            _Pragma("unroll") for (int kk = 0; kk < 2; ++kk)                  \
                acc[(mh_) * 4 + m][(nh_) * 2 + n] =                           \
                    __builtin_amdgcn_mfma_f32_16x16x32_bf16(                  \
                        af[m * 2 + kk], bfr[((nh_) * 2 + n) * 2 + kk],        \
                        acc[(mh_) * 4 + m][(nh_) * 2 + n], 0, 0, 0);          \
  } while (0)

  // --- prologue: tile0 + B(1) + A(1)h0 issued; VM(6) -> tile0 landed,
  //     3 half-tiles (B1h0, B1h1, A1h0) in flight = steady state ---
  STAGE_A(0, 0, 0); STAGE_A(0, 1, 0);
  STAGE_B(0, 0, 0); STAGE_B(0, 1, 0);
  STAGE_B(1, 0, 1); STAGE_B(1, 1, 1);
  STAGE_A(1, 0, 1);
  VM(6);
  BAR();

  // --- main loop: 4 phases / K-tile, 1 half-tile stage per phase ---
  // WAR ledger: A[b]h0 free after P1 reads (regs hold frags), h1 after P3;
  //             B[b]h0 free after P1, h1 after P2. Stages placed at/after free.
  // RAW: VM(6) at P4(t) leaves exactly {B(t+2)h0,h1, A(t+2)h0} -> tile t+1 landed.
  for (int t = 0; t < NT; ++t) {
    const int bsel = t & 1;
    // P1: quadrant (m0, n0); stage A(t+1) h1 (buf bsel^1, freed at P3(t-1))
    RD_A(0); RD_B(0);
    if (t + 1 < NT) STAGE_A(bsel ^ 1, 1, t + 1);
    BAR(); LGKM0();
    __builtin_amdgcn_s_setprio(1); QUAD(0, 0); __builtin_amdgcn_s_setprio(0);
    BAR();
    // P2: (m0, n1); stage B(t+2) h0 (buf bsel, h0 last ds_read at P1(t))
    RD_B(1);
    if (t + 2 < NT) STAGE_B(bsel, 0, t + 2);
    BAR(); LGKM0();
    __builtin_amdgcn_s_setprio(1); QUAD(0, 1); __builtin_amdgcn_s_setprio(0);
    BAR();
    // P3: (m1, n1); stage B(t+2) h1 (h1 last ds_read at P2(t))
    RD_A(1);
    if (t + 2 < NT) STAGE_B(bsel, 1, t + 2);
    BAR(); LGKM0();
    __builtin_amdgcn_s_setprio(1); QUAD(1, 1); __builtin_amdgcn_s_setprio(0);
    BAR();
    // P4: (m1, n0) — B-frags from regs; stage A(t+2) h0 (h0 last ds_read at P1(t))
    if (t + 2 < NT) STAGE_A(bsel, 0, t + 2);
    BAR(); LGKM0();
    __builtin_amdgcn_s_setprio(1); QUAD(1, 0); __builtin_amdgcn_s_setprio(0);
    if (t < NT - 2) { VM(6); } else { VM(0); }
    BAR();
  }

  // --- epilogue: C/D layout col=lane&15, row=(lane>>4)*4+reg; fuse scale+bias ---
  const int row0 = bm * 256 + wr * 128 + ((l >> 4) << 2);
  const int col0 = bn * 256 + wc * 64 + (l & 15);
#pragma unroll
  for (int fn = 0; fn < 4; ++fn) {
    const int col = col0 + fn * 16;
    const float sc = scales[col];
    const float bi = bias[col];
#pragma unroll
    for (int fm = 0; fm < 8; ++fm) {
      float* cp = C + (size_t)(row0 + fm * 16) * N_TOTAL + col;
#pragma unroll
      for (int j = 0; j < 4; ++j) cp[(size_t)j * N_TOTAL] = fmaf(acc[fm][fn][j], sc, bi);
    }
  }
}

// ---- guarded fallback (only if d_ws too small) ----
__global__ void naive_gemm(const float* __restrict__ A, const int* __restrict__ W,
                           const float* __restrict__ scales, const float* __restrict__ bias,
                           float* __restrict__ C) {
  size_t idx = (size_t)blockIdx.x * blockDim.x + threadIdx.x;
  if (idx >= (size_t)M_TOTAL * N_TOTAL) return;
  const int n = (int)(idx % N_TOTAL);
  const size_t m = idx / N_TOTAL;
  const float* a = A + m * (size_t)K_TOTAL;
  const int* w = W + (size_t)n * K_TOTAL;
  float s = 0.f;
  for (int k = 0; k < K_TOTAL; ++k) s = fmaf(a[k], (float)w[k], s);
  C[idx] = fmaf(s, scales[n], bias[n]);
}

extern "C" void kernel_launch(void* const* d_in, const int* in_sizes, int n_in,
                              void* d_out, int out_size, void* d_ws, size_t ws_size,
                              hipStream_t stream) {
  const float* A = (const float*)d_in[0];
  const int* W = (const int*)d_in[1];
  const float* scales = (const float*)d_in[2];
  const float* bias = (const float*)d_in[3];
  float* out = (float*)d_out;

  const size_t a_elems = (size_t)M_TOTAL * K_TOTAL;
  const size_t w_elems = (size_t)N_TOTAL * K_TOTAL;
  const size_t need = (a_elems + w_elems) * sizeof(unsigned short);

  if (ws_size >= need) {
    unsigned short* A_bf = (unsigned short*)d_ws;
    unsigned short* W_bf = A_bf + a_elems;
    cvt_f32_bf16<<<2048, 256, 0, stream>>>(A, (u16x8*)A_bf, (int)(a_elems / 8));
    cvt_i32_bf16<<<2048, 256, 0, stream>>>(W, (u16x8*)W_bf, (int)(w_elems / 8));
    dim3 grid(N_TOTAL / 256, M_TOTAL / 256);  // (16, 64)
    w8a16_gemm256<<<grid, 512, 0, stream>>>(A_bf, W_bf, scales, bias, out);
  } else {
    size_t total = (size_t)M_TOTAL * N_TOTAL;
    naive_gemm<<<(unsigned)((total + 255) / 256), 256, 0, stream>>>(A, W, scales, bias, out);
  }
}

// Round 6
// 379.426 us; speedup vs baseline: 1.4750x; 1.4750x over previous
//
#include <hip/hip_runtime.h>
#include <hip/hip_bf16.h>

// out[B,S,O] = A[B,S,I] @ W[O,I]^T * scales[O] + bias[O]
// M = 16384, N = 4096, K = 4096. Output fp32.
// Strategy: quantize A to int8 per-row (scale amax/127), W is already int8-
// valued; GEMM via mfma_i32_16x16x64_i8 (2x bf16 rate, exact i32 accum),
// dequant in epilogue: out = acc * (arow_scale[m] * scales[n]) + bias[n].
#define M_TOTAL 16384
#define N_TOTAL 4096
#define K_TOTAL 4096
#define NT (K_TOTAL / 128)  // 32 K-tiles of BK=128 (i8)

typedef __attribute__((ext_vector_type(4))) int i32x4;
typedef __attribute__((ext_vector_type(4))) float f32x4;

// ---- A quantization: one block per row, row held in registers ----
__global__ __launch_bounds__(256) void quant_a(const float* __restrict__ A,
                                               signed char* __restrict__ Aq,
                                               float* __restrict__ ascale) {
  const int row = blockIdx.x;
  const int tid = threadIdx.x;
  const float4* src = reinterpret_cast<const float4*>(A + (size_t)row * K_TOTAL) + tid * 4;
  float4 v0 = src[0], v1 = src[1], v2 = src[2], v3 = src[3];
  float m0 = fmaxf(fmaxf(fabsf(v0.x), fabsf(v0.y)), fmaxf(fabsf(v0.z), fabsf(v0.w)));
  float m1 = fmaxf(fmaxf(fabsf(v1.x), fabsf(v1.y)), fmaxf(fabsf(v1.z), fabsf(v1.w)));
  float m2 = fmaxf(fmaxf(fabsf(v2.x), fabsf(v2.y)), fmaxf(fabsf(v2.z), fabsf(v2.w)));
  float m3 = fmaxf(fmaxf(fabsf(v3.x), fabsf(v3.y)), fmaxf(fabsf(v3.z), fabsf(v3.w)));
  float amax = fmaxf(fmaxf(m0, m1), fmaxf(m2, m3));
#pragma unroll
  for (int off = 32; off > 0; off >>= 1) amax = fmaxf(amax, __shfl_xor(amax, off, 64));
  __shared__ float wmax[4];
  if ((tid & 63) == 0) wmax[tid >> 6] = amax;
  __syncthreads();
  amax = fmaxf(fmaxf(wmax[0], wmax[1]), fmaxf(wmax[2], wmax[3]));
  amax = fmaxf(amax, 1e-20f);
  const float rs = 127.0f / amax;
  if (tid == 0) ascale[row] = amax * (1.0f / 127.0f);

  int q[16];
  float a[16] = {v0.x, v0.y, v0.z, v0.w, v1.x, v1.y, v1.z, v1.w,
                 v2.x, v2.y, v2.z, v2.w, v3.x, v3.y, v3.z, v3.w};
#pragma unroll
  for (int i = 0; i < 16; ++i) {
    int t = (int)rintf(a[i] * rs);
    q[i] = t < -127 ? -127 : (t > 127 ? 127 : t);
  }
  i32x4 packed;
#pragma unroll
  for (int d = 0; d < 4; ++d)
    packed[d] = (q[d * 4] & 0xFF) | ((q[d * 4 + 1] & 0xFF) << 8) |
                ((q[d * 4 + 2] & 0xFF) << 16) | ((q[d * 4 + 3] & 0xFF) << 24);
  reinterpret_cast<i32x4*>(Aq + (size_t)row * K_TOTAL)[tid] = packed;
}

// ---- W int32 -> int8 (values already in [-127,127]) ----
__global__ void cvt_w_i8(const int* __restrict__ W, signed char* __restrict__ Wq, int n16) {
  const int stride = gridDim.x * blockDim.x;
  for (int i = blockIdx.x * blockDim.x + threadIdx.x; i < n16; i += stride) {
    const int4* p = reinterpret_cast<const int4*>(W) + (size_t)4 * i;
    i32x4 o;
#pragma unroll
    for (int d = 0; d < 4; ++d) {
      int4 v = p[d];
      o[d] = (v.x & 0xFF) | ((v.y & 0xFF) << 8) | ((v.z & 0xFF) << 16) | ((v.w & 0xFF) << 24);
    }
    reinterpret_cast<i32x4*>(Wq)[i] = o;
  }
}

// ======== 256x256 i8 GEMM — byte-exact port of the R3-proven skeleton ========
// BK=128 i8 rows = 128 B = identical byte geometry to the verified bf16 kernel:
// same LDS map, same (r&7)<<4 swizzle, same staging, same 4-phase schedule.
#define GLOAD_LDS16(gp, lp)                                                \
  __builtin_amdgcn_global_load_lds(                                        \
      (const __attribute__((address_space(1))) void*)(gp),                 \
      (__attribute__((address_space(3))) void*)(lp), 16, 0, 0)

#define BAR() asm volatile("s_barrier" ::: "memory")
#define LGKM0() asm volatile("s_waitcnt lgkmcnt(0)" ::: "memory")
#define VM(n) asm volatile("s_waitcnt vmcnt(" #n ")" ::: "memory")

// LDS map (131072 B): buf b: A_h0 [0,16K) A_h1 [16K,32K) B_h0 [32K,48K) B_h1 [48K,64K); buf1 at +64K.
// Half-tile = 128 rows x 128 i8 cols, row stride 128 B.
// Swizzle: (r,c) at byte r*128 + (c ^ ((r&7)<<4)) (involution, 16B blocks).
// gload_lds writes linearly; GLOBAL source pre-inverse-swizzled (rule #21).

__global__ __launch_bounds__(512, 2) void w8a16_gemm_i8(
    const signed char* __restrict__ A,   // [M][K] i8
    const signed char* __restrict__ Bt,  // [N][K] i8
    const float* __restrict__ ascale,    // [M] dequant scale for A rows
    const float* __restrict__ scales, const float* __restrict__ bias,
    float* __restrict__ C) {
  __shared__ alignas(16) unsigned char lds[131072];

  const int tid = threadIdx.x;
  const int w = tid >> 6, l = tid & 63;
  const int wr = w >> 2, wc = w & 3;  // 2x4 wave grid; per-wave 128x64 output
  const int bn = blockIdx.x, bm = blockIdx.y;

  // --- staging (pre-inverse-swizzled global source) ---
  const int rowq = tid >> 3;                   // w*8 + (l>>3), 0..63
  const int colb = ((l & 7) ^ (l >> 3)) << 4;  // col byte block
  const signed char* pA = A + (size_t)(bm * 256 + rowq) * K_TOTAL + colb;
  const signed char* pB = Bt + (size_t)(bn * 256 + rowq) * K_TOTAL + colb;
  unsigned char* const ldsp = lds;
  const int woff = w << 10;

#define SDA(b_, h_) (ldsp + (b_) * 65536 + (h_) * 16384 + woff)
#define SDB(b_, h_) (ldsp + (b_) * 65536 + 32768 + (h_) * 16384 + woff)
#define STAGE_A(b_, h_, t_)                                                    \
  do {                                                                         \
    GLOAD_LDS16(pA + (size_t)((h_) * 128) * K_TOTAL + (t_) * 128, SDA(b_, h_));\
    GLOAD_LDS16(pA + (size_t)((h_) * 128 + 64) * K_TOTAL + (t_) * 128,         \
                SDA(b_, h_) + 8192);                                           \
  } while (0)
#define STAGE_B(b_, h_, t_)                                                    \
  do {                                                                         \
    GLOAD_LDS16(pB + (size_t)((h_) * 128) * K_TOTAL + (t_) * 128, SDB(b_, h_));\
    GLOAD_LDS16(pB + (size_t)((h_) * 128 + 64) * K_TOTAL + (t_) * 128,         \
                SDB(b_, h_) + 8192);                                           \
  } while (0)

  // --- fragment reads (swizzled): frag row = f*16 + (l&15); 16B k-block at
  //     kk*64 + (l>>4)*16, swizzled by ((l&15)&7)<<4 ---
  const int arow = ((l & 15) << 7) + ((((l >> 4) ^ (l & 7)) & 7) << 4);

  i32x4 af[8];   // 4 m-frags x 2 kk (current m-half); 16 i8 each, k=(l>>4)*16+j
  i32x4 bfr[8];  // 4 n-frags x 2 kk (whole tile)
  i32x4 acc[8][4] = {{}};

#define RD_A(mh_)                                                             \
  do {                                                                        \
    const unsigned char* Ab_ = ldsp + bsel * 65536 + wr * 16384;              \
    _Pragma("unroll") for (int fm = 0; fm < 4; ++fm)                          \
        _Pragma("unroll") for (int kk = 0; kk < 2; ++kk)                      \
            af[fm * 2 + kk] = *(const i32x4*)(Ab_ + ((mh_) * 4 + fm) * 2048 + \
                                              (arow ^ (kk << 6)));            \
  } while (0)
#define RD_B(nh_)                                                             \
  do {                                                                        \
    const unsigned char* Bb_ = ldsp + bsel * 65536 + 32768 +                  \
                               (wc >> 1) * 16384 + (wc & 1) * 8192;           \
    _Pragma("unroll") for (int fn = 0; fn < 2; ++fn)                          \
        _Pragma("unroll") for (int kk = 0; kk < 2; ++kk)                      \
            bfr[((nh_) * 2 + fn) * 2 + kk] =                                  \
                *(const i32x4*)(Bb_ + ((nh_) * 2 + fn) * 2048 +               \
                                (arow ^ (kk << 6)));                          \
  } while (0)
#define QUAD(mh_, nh_)                                                        \
  do {                                                                        \
    __builtin_amdgcn_s_setprio(1);                                            \
    _Pragma("unroll") for (int m = 0; m < 4; ++m)                             \
        _Pragma("unroll") for (int n = 0; n < 2; ++n)                         \
            _Pragma("unroll") for (int kk = 0; kk < 2; ++kk)                  \
                acc[(mh_) * 4 + m][(nh_) * 2 + n] =                           \
                    __builtin_amdgcn_mfma_i32_16x16x64_i8(                    \
                        af[m * 2 + kk], bfr[((nh_) * 2 + n) * 2 + kk],        \
                        acc[(mh_) * 4 + m][(nh_) * 2 + n], 0, 0, 0);          \
    __builtin_amdgcn_s_setprio(0);                                            \
  } while (0)

  // --- prologue: tile0 + B(1) + A(1)h0; VM(6) drains tile0; fence-before-BAR ---
  STAGE_A(0, 0, 0); STAGE_A(0, 1, 0);
  STAGE_B(0, 0, 0); STAGE_B(0, 1, 0);
  STAGE_B(1, 0, 1); STAGE_B(1, 1, 1);
  STAGE_A(1, 0, 1);
  VM(6);
  BAR();

  // --- main loop (R3-proven): 4 phases/tile, reads in consuming phase ---
  // Ledger at P1 head: outstanding {Bh0(t+1),Bh1(t+1),Ah0(t+1)}=6, tile t landed.
  // VM(6)@P4-end completes tile t+1 (incl. Ah1(t+1) staged at P1) exactly.
  for (int t = 0; t < NT; ++t) {
    const int bsel = t & 1;
    // P1
    RD_A(0); RD_B(0);
    if (t + 1 < NT) STAGE_A(bsel ^ 1, 1, t + 1);
    BAR(); LGKM0();
    QUAD(0, 0);
    BAR();
    // P2
    RD_B(1);
    if (t + 2 < NT) STAGE_B(bsel, 0, t + 2);
    BAR(); LGKM0();
    QUAD(0, 1);
    BAR();
    // P3
    RD_A(1);
    if (t + 2 < NT) STAGE_B(bsel, 1, t + 2);
    BAR(); LGKM0();
    QUAD(1, 1);
    BAR();
    // P4 (B-frags reused from registers)
    if (t + 2 < NT) STAGE_A(bsel, 0, t + 2);
    BAR(); LGKM0();
    QUAD(1, 0);
    if (t < NT - 2) { VM(6); } else { VM(0); }
    BAR();
  }

  // --- epilogue: C/D col=lane&15, row=(lane>>4)*4+reg (dtype-independent,
  //     HW-verified for i8); dequant acc * (ascale[row]*scales[col]) + bias ---
  const int row0 = bm * 256 + wr * 128 + ((l >> 4) << 2);
  const int col0 = bn * 256 + wc * 64 + (l & 15);
#pragma unroll
  for (int fn = 0; fn < 4; ++fn) {
    const int col = col0 + fn * 16;
    const float sc = scales[col];
    const float bi = bias[col];
#pragma unroll
    for (int fm = 0; fm < 8; ++fm) {
      const int r = row0 + fm * 16;
      float* cp = C + (size_t)r * N_TOTAL + col;
#pragma unroll
      for (int j = 0; j < 4; ++j)
        cp[(size_t)j * N_TOTAL] = fmaf((float)acc[fm][fn][j], ascale[r + j] * sc, bi);
    }
  }
}

// ---- guarded fallback (only if d_ws too small) ----
__global__ void naive_gemm(const float* __restrict__ A, const int* __restrict__ W,
                           const float* __restrict__ scales, const float* __restrict__ bias,
                           float* __restrict__ C) {
  size_t idx = (size_t)blockIdx.x * blockDim.x + threadIdx.x;
  if (idx >= (size_t)M_TOTAL * N_TOTAL) return;
  const int n = (int)(idx % N_TOTAL);
  const size_t m = idx / N_TOTAL;
  const float* a = A + m * (size_t)K_TOTAL;
  const int* w = W + (size_t)n * K_TOTAL;
  float s = 0.f;
  for (int k = 0; k < K_TOTAL; ++k) s = fmaf(a[k], (float)w[k], s);
  C[idx] = fmaf(s, scales[n], bias[n]);
}

extern "C" void kernel_launch(void* const* d_in, const int* in_sizes, int n_in,
                              void* d_out, int out_size, void* d_ws, size_t ws_size,
                              hipStream_t stream) {
  const float* A = (const float*)d_in[0];
  const int* W = (const int*)d_in[1];
  const float* scales = (const float*)d_in[2];
  const float* bias = (const float*)d_in[3];
  float* out = (float*)d_out;

  const size_t a_elems = (size_t)M_TOTAL * K_TOTAL;  // 67,108,864
  const size_t w_elems = (size_t)N_TOTAL * K_TOTAL;  // 16,777,216
  const size_t need = a_elems + w_elems + (size_t)M_TOTAL * sizeof(float);

  if (ws_size >= need) {
    signed char* A_q = (signed char*)d_ws;
    signed char* W_q = A_q + a_elems;
    float* a_s = (float*)(W_q + w_elems);
    quant_a<<<M_TOTAL, 256, 0, stream>>>(A, A_q, a_s);
    cvt_w_i8<<<2048, 256, 0, stream>>>(W, W_q, (int)(w_elems / 16));
    dim3 grid(N_TOTAL / 256, M_TOTAL / 256);  // (16, 64)
    w8a16_gemm_i8<<<grid, 512, 0, stream>>>(A_q, W_q, a_s, scales, bias, out);
  } else {
    size_t total = (size_t)M_TOTAL * N_TOTAL;
    naive_gemm<<<(unsigned)((total + 255) / 256), 256, 0, stream>>>(A, W, scales, bias, out);
  }
}